// Round 8
// baseline (502.549 us; speedup 1.0000x reference)
//
#include <hip/hip_runtime.h>
#include <hip/hip_bf16.h>
#include <stdint.h>

// QuantizedLinear: out_f32[512,16384] = x_f32[512,4096] @ (qw_i32 * scales)^T + bias
// dtypes (verified round 3): x fp32, qw int32, scales fp32, bias fp32, out fp32.
//
// Round-8: force the prefetch to BE a prefetch.
// Evidence: round-4 gemm reported VGPR_Count=48, impossible with the A-fragment
// array live as written (>=90) -> the compiler sinks global loads to their use
// points (register-pressure-minimizing scheduler). Hence r6/r7's issue-early
// restructurings changed source order, not emitted order, and per-iter time
// equals the SUM of wire+LDS+MFMA. Fix: a single __builtin_amdgcn_sched_barrier(0)
// between the next-iter load-issue block and the compute phase, so the loads
// stay issued ~2.5k cycles before their waits and the wire time overlaps MFMA.
// Everything else identical to round 7 (passed, absmax 0.125).

#define MM 512
#define NN 16384
#define KK 4096
#define BN 64
#define BK 128
#define NKB (KK / BK)   // 32

typedef __bf16 bf16x8 __attribute__((ext_vector_type(8)));
typedef float floatx4 __attribute__((ext_vector_type(4)));

__device__ __forceinline__ void barrier_nodrain() {
    // LDS handoff needs lgkmcnt(0); deliberately NO vmcnt drain.
    asm volatile("s_waitcnt lgkmcnt(0)\n\ts_barrier" ::: "memory");
}

__device__ __forceinline__ unsigned int pk_bf16_rtn(float lo, float hi) {
    __hip_bfloat162 h = __float22bfloat162_rn(float2{lo, hi});
    return *reinterpret_cast<unsigned int*>(&h);
}

// ---- prepass: x fp32 -> bf16, packed in MFMA A-fragment order ----
// xp element index: (((kb*4 + ks)*32 + mt)*64 + lane)*8,
//   holding x[mt*16 + (lane&15)][kb*128 + ks*32 + (lane>>4)*8 .. +8]
__global__ __launch_bounds__(256) void pack_x(const float* __restrict__ x,
                                              unsigned short* __restrict__ xp) {
    const int t    = blockIdx.x * 256 + threadIdx.x;   // 0..262143
    const int lane = t & 63;
    const int mt   = (t >> 6) & 31;
    const int ks   = (t >> 11) & 3;
    const int kb   = t >> 13;
    const int m    = mt * 16 + (lane & 15);
    const int k    = kb * 128 + ks * 32 + (lane >> 4) * 8;
    const float* px = x + (size_t)m * KK + k;
    const float4 a = *(const float4*)px;
    const float4 b = *(const float4*)(px + 4);
    uint4 o;
    o.x = pk_bf16_rtn(a.x, a.y);
    o.y = pk_bf16_rtn(a.z, a.w);
    o.z = pk_bf16_rtn(b.x, b.y);
    o.w = pk_bf16_rtn(b.z, b.w);
    *(uint4*)(xp + (size_t)t * 8) = o;   // fully coalesced 16B/thread
}

template <bool PRE>
__global__ __launch_bounds__(1024, 4) void qlin_gemm(
    const float* __restrict__ xf,               // fp32 x (fallback path)
    const unsigned short* __restrict__ xp,      // packed bf16 x (prepass path)
    const int* __restrict__ qw,                 // int32 [16384,4096]
    const float* __restrict__ scales,           // fp32 [16384,64]
    const float* __restrict__ bias,             // fp32 [16384]
    float* __restrict__ out)                    // fp32 [512,16384]
{
    __shared__ unsigned short sB[2][BN * BK];   // fragment-ordered + swizzled, 2 x 16 KB

    const int t    = threadIdx.x;
    const int lane = t & 63;
    const int w    = t >> 6;          // wave 0..15 -> M strip [w*32, w*32+32)
    const int ln   = lane & 15;
    const int quad = lane >> 4;
    const int n0   = blockIdx.x * BN;

    // ---- producer mapping: thread t -> qw row (t>>4), k-octet (t&15) ----
    const int r    = t >> 4;          // 0..63
    const int oct  = t & 15;
    const int ksp  = oct >> 2;        // frag k-slice 0..3
    const int jp   = r >> 4;          // frag col-tile 0..3
    const int ldst = (((oct & 3) << 4) | (r & 15)) ^ (ksp << 1);   // swizzled frag lane
    const int woff = ((ksp * 4 + jp) * 64 + ldst) * 8;
    const int* qp  = qw + (size_t)(n0 + r) * KK + oct * 8;
    const float* sp = scales + (size_t)(n0 + r) * 64 + (oct >> 3);

    floatx4 acc[2][4];
#pragma unroll
    for (int i = 0; i < 2; ++i)
#pragma unroll
        for (int j = 0; j < 4; ++j)
            acc[i][j] = (floatx4)0.0f;

    // ---- prologue: qw(0) + A(0) in flight ----
    int4 qv0 = *(const int4*)(qp);
    int4 qv1 = *(const int4*)(qp + 4);
    float s  = sp[0];

    bf16x8 a[2][4][2];   // [buf][ks][i] -- A register double-buffer
    if constexpr (PRE) {
#pragma unroll
        for (int ks = 0; ks < 4; ++ks) {
            const unsigned short* ap = xp + (size_t)((ks * 32 + w * 2) * 64 + lane) * 8;
            a[0][ks][0] = *(const bf16x8*)(ap);
            a[0][ks][1] = *(const bf16x8*)(ap + 512);
        }
    }

#pragma unroll 2
    for (int kb = 0; kb < NKB; ++kb) {
        const int cur = kb & 1;
        unsigned short* sb = sB[cur];

        // ---- dequant qw(kb) (loaded one full iteration ago) into LDS ----
        uint4 u;
        u.x = pk_bf16_rtn((float)qv0.x * s, (float)qv0.y * s);
        u.y = pk_bf16_rtn((float)qv0.z * s, (float)qv0.w * s);
        u.z = pk_bf16_rtn((float)qv1.x * s, (float)qv1.y * s);
        u.w = pk_bf16_rtn((float)qv1.z * s, (float)qv1.w * s);
        *(uint4*)(sb + woff) = u;     // one conflict-free ds_write_b128

        barrier_nodrain();   // lgkm drain only -- global streams stay in flight

        // ---- issue NEXT iteration's streams; fence below forbids sinking ----
        if (kb + 1 < NKB) {
            qv0 = *(const int4*)(qp + (size_t)(kb + 1) * BK);
            qv1 = *(const int4*)(qp + (size_t)(kb + 1) * BK + 4);
            s   = sp[(size_t)(kb + 1) * 2];
            if constexpr (PRE) {
                const unsigned short* xpb = xp + (size_t)(kb + 1) * (4 * 32 * 64 * 8);
#pragma unroll
                for (int ks = 0; ks < 4; ++ks) {
                    const unsigned short* ap = xpb + (size_t)((ks * 32 + w * 2) * 64 + lane) * 8;
                    a[cur ^ 1][ks][0] = *(const bf16x8*)(ap);
                    a[cur ^ 1][ks][1] = *(const bf16x8*)(ap + 512);
                }
            }
        }
        // scheduling fence: prefetch loads may NOT be sunk into/below compute
        __builtin_amdgcn_sched_barrier(0);

        // ---- compute kb from LDS B + register A ----
#pragma unroll
        for (int ks = 0; ks < 4; ++ks) {
            bf16x8 a0, a1;
            if constexpr (PRE) {
                a0 = a[cur][ks][0];
                a1 = a[cur][ks][1];
            } else {
                const int k = kb * BK + ks * 32 + quad * 8;
#pragma unroll
                for (int i = 0; i < 2; ++i) {
                    const float* px = xf + (size_t)(w * 32 + i * 16 + ln) * KK + k;
                    const float4 f0 = *(const float4*)px;
                    const float4 f1 = *(const float4*)(px + 4);
                    uint4 ua;
                    ua.x = pk_bf16_rtn(f0.x, f0.y);
                    ua.y = pk_bf16_rtn(f0.z, f0.w);
                    ua.z = pk_bf16_rtn(f1.x, f1.y);
                    ua.w = pk_bf16_rtn(f1.z, f1.w);
                    if (i == 0) a0 = *(bf16x8*)&ua; else a1 = *(bf16x8*)&ua;
                }
            }
            bf16x8 bfr[4];
#pragma unroll
            for (int j = 0; j < 4; ++j)
                bfr[j] = *(const bf16x8*)(sb + ((ks * 4 + j) * 64 + (lane ^ (ks << 1))) * 8);
#pragma unroll
            for (int j = 0; j < 4; ++j) {
                acc[0][j] = __builtin_amdgcn_mfma_f32_16x16x32_bf16(a0, bfr[j], acc[0][j], 0, 0, 0);
                acc[1][j] = __builtin_amdgcn_mfma_f32_16x16x32_bf16(a1, bfr[j], acc[1][j], 0, 0, 0);
            }
        }
        // no trailing barrier: next iter writes the OTHER LDS buffer
    }

    // ---- epilogue: + bias, store fp32 ----
#pragma unroll
    for (int j = 0; j < 4; ++j) {
        const int n = n0 + j * 16 + ln;
        const float bv = bias[n];
#pragma unroll
        for (int i = 0; i < 2; ++i) {
            const int mbase = w * 32 + i * 16 + quad * 4;
#pragma unroll
            for (int rr = 0; rr < 4; ++rr)
                out[(size_t)(mbase + rr) * NN + n] = acc[i][j][rr] + bv;
        }
    }
}

extern "C" void kernel_launch(void* const* d_in, const int* in_sizes, int n_in,
                              void* d_out, int out_size, void* d_ws, size_t ws_size,
                              hipStream_t stream) {
    const float* x    = (const float*)d_in[0];
    const int* qw     = (const int*)d_in[1];
    const float* scl  = (const float*)d_in[2];
    const float* bias = (const float*)d_in[3];
    float* out        = (float*)d_out;

    dim3 grid(NN / BN);    // 256 blocks: one 64-col slab each, all 512 rows
    dim3 block(1024);      // 16 waves

    if (ws_size >= (size_t)MM * KK * sizeof(unsigned short)) {
        unsigned short* xp = (unsigned short*)d_ws;
        pack_x<<<dim3(MM * KK / (256 * 8)), dim3(256), 0, stream>>>(x, xp);
        qlin_gemm<true><<<grid, block, 0, stream>>>(x, xp, qw, scl, bias, out);
    } else {
        qlin_gemm<false><<<grid, block, 0, stream>>>(x, nullptr, qw, scl, bias, out);
    }
}

// Round 9
// 446.793 us; speedup vs baseline: 1.1248x; 1.1248x over previous
//
#include <hip/hip_runtime.h>
#include <hip/hip_bf16.h>
#include <stdint.h>

// QuantizedLinear: out_f32[512,16384] = x_f32[512,4096] @ (qw_i32 * scales)^T + bias
// dtypes (verified round 3): x fp32, qw int32, scales fp32, bias fp32, out fp32.
//
// Round-9: stop hand-pipelining; get overlap from TWO desynchronized blocks/CU.
// r6-r8 evidence: within one 16-wave barrier domain every pipelining trick is
// neutral (scheduler sinks loads) or regresses (sched_barrier -> 270 MB scratch
// spill). m97's overlap comes from multiple co-resident blocks. So:
//   - grid 512 x 512 threads (8 waves), BN=32 -> qw still read exactly ONCE
//     (blocks own disjoint qw rows); 2 blocks/CU (16 KB LDS, VGPR<=128).
//   - wave tile M=64 x N=32 (acc 4x2): B-frag reads halved vs round 8.
//   - qw loaded NON-TEMPORAL (evict-first): the 256 MB stream stops thrashing
//     x (4 MB, one XCD L2) out of L2.
//   - keep: swizzled fragment-order B LDS (conflict-free), packed-x prepass,
//     1-deep qw register prefetch, lgkm-only barrier. No sched fences.

#define MM 512
#define NN 16384
#define KK 4096
#define BN 32
#define BK 128
#define NKB (KK / BK)   // 32

typedef __bf16 bf16x8 __attribute__((ext_vector_type(8)));
typedef float floatx4 __attribute__((ext_vector_type(4)));
typedef int intx4 __attribute__((ext_vector_type(4)));

__device__ __forceinline__ void barrier_nodrain() {
    // LDS handoff needs lgkmcnt(0); deliberately NO vmcnt drain.
    asm volatile("s_waitcnt lgkmcnt(0)\n\ts_barrier" ::: "memory");
}

__device__ __forceinline__ unsigned int pk_bf16_rtn(float lo, float hi) {
    __hip_bfloat162 h = __float22bfloat162_rn(float2{lo, hi});
    return *reinterpret_cast<unsigned int*>(&h);
}

// ---- prepass: x fp32 -> bf16, packed in MFMA A-fragment order ----
// xp element index: (((kb*4 + ks)*32 + mt)*64 + lane)*8,
//   holding x[mt*16 + (lane&15)][kb*128 + ks*32 + (lane>>4)*8 .. +8]
__global__ __launch_bounds__(256) void pack_x(const float* __restrict__ x,
                                              unsigned short* __restrict__ xp) {
    const int t    = blockIdx.x * 256 + threadIdx.x;   // 0..262143
    const int lane = t & 63;
    const int mt   = (t >> 6) & 31;
    const int ks   = (t >> 11) & 3;
    const int kb   = t >> 13;
    const int m    = mt * 16 + (lane & 15);
    const int k    = kb * 128 + ks * 32 + (lane >> 4) * 8;
    const float* px = x + (size_t)m * KK + k;
    const float4 a = *(const float4*)px;
    const float4 b = *(const float4*)(px + 4);
    uint4 o;
    o.x = pk_bf16_rtn(a.x, a.y);
    o.y = pk_bf16_rtn(a.z, a.w);
    o.z = pk_bf16_rtn(b.x, b.y);
    o.w = pk_bf16_rtn(b.z, b.w);
    *(uint4*)(xp + (size_t)t * 8) = o;   // fully coalesced 16B/thread
}

template <bool PRE>
__global__ __launch_bounds__(512, 4) void qlin_gemm(
    const float* __restrict__ xf,               // fp32 x (fallback path)
    const unsigned short* __restrict__ xp,      // packed bf16 x (prepass path)
    const int* __restrict__ qw,                 // int32 [16384,4096]
    const float* __restrict__ scales,           // fp32 [16384,64]
    const float* __restrict__ bias,             // fp32 [16384]
    float* __restrict__ out)                    // fp32 [512,16384]
{
    __shared__ unsigned short sB[2][BN * BK];   // fragment-ordered + swizzled, 2 x 8 KB

    const int t    = threadIdx.x;
    const int lane = t & 63;
    const int w    = t >> 6;          // wave 0..7 -> M strip [w*64, w*64+64)
    const int ln   = lane & 15;
    const int quad = lane >> 4;
    const int n0   = blockIdx.x * BN;

    // ---- producer mapping: thread t -> qw row (t>>4) (0..31), k-octet (t&15) ----
    const int r    = t >> 4;          // 0..31
    const int oct  = t & 15;
    const int ksp  = oct >> 2;        // frag k-slice 0..3
    const int jp   = r >> 4;          // frag col-tile 0..1
    const int ldst = (((oct & 3) << 4) | (r & 15)) ^ (ksp << 1);   // swizzled frag lane
    const int woff = ((ksp * 2 + jp) * 64 + ldst) * 8;
    const int* qp  = qw + (size_t)(n0 + r) * KK + oct * 8;
    const float* sp = scales + (size_t)(n0 + r) * 64 + (oct >> 3);

    floatx4 acc[4][2];
#pragma unroll
    for (int i = 0; i < 4; ++i)
#pragma unroll
        for (int j = 0; j < 2; ++j)
            acc[i][j] = (floatx4)0.0f;

    // ---- prologue: qw(0) in flight (non-temporal: don't thrash x in L2) ----
    intx4 qv0 = __builtin_nontemporal_load((const intx4*)(qp));
    intx4 qv1 = __builtin_nontemporal_load((const intx4*)(qp + 4));
    float s  = sp[0];

    for (int kb = 0; kb < NKB; ++kb) {
        unsigned short* sb = sB[kb & 1];

        // ---- dequant qw(kb) (loaded one iteration ago) into LDS ----
        uint4 u;
        u.x = pk_bf16_rtn((float)qv0.x * s, (float)qv0.y * s);
        u.y = pk_bf16_rtn((float)qv0.z * s, (float)qv0.w * s);
        u.z = pk_bf16_rtn((float)qv1.x * s, (float)qv1.y * s);
        u.w = pk_bf16_rtn((float)qv1.z * s, (float)qv1.w * s);
        *(uint4*)(sb + woff) = u;     // one conflict-free ds_write_b128

        barrier_nodrain();   // lgkm drain only

        // ---- issue next iteration's qw stream ----
        if (kb + 1 < NKB) {
            qv0 = __builtin_nontemporal_load((const intx4*)(qp + (size_t)(kb + 1) * BK));
            qv1 = __builtin_nontemporal_load((const intx4*)(qp + (size_t)(kb + 1) * BK + 4));
            s   = sp[(size_t)(kb + 1) * 2];
        }

        // ---- compute kb: A from global (L2-hot), B from LDS ----
        const unsigned short* xpb = xp + (size_t)kb * (4 * 32 * 64 * 8);
#pragma unroll
        for (int ks = 0; ks < 4; ++ks) {
            bf16x8 a[4];
            if constexpr (PRE) {
#pragma unroll
                for (int i = 0; i < 4; ++i)
                    a[i] = *(const bf16x8*)(xpb + (size_t)((ks * 32 + w * 4 + i) * 64 + lane) * 8);
            } else {
                const int k = kb * BK + ks * 32 + quad * 8;
#pragma unroll
                for (int i = 0; i < 4; ++i) {
                    const float* px = xf + (size_t)(w * 64 + i * 16 + ln) * KK + k;
                    const float4 f0 = *(const float4*)px;
                    const float4 f1 = *(const float4*)(px + 4);
                    uint4 ua;
                    ua.x = pk_bf16_rtn(f0.x, f0.y);
                    ua.y = pk_bf16_rtn(f0.z, f0.w);
                    ua.z = pk_bf16_rtn(f1.x, f1.y);
                    ua.w = pk_bf16_rtn(f1.z, f1.w);
                    a[i] = *(bf16x8*)&ua;
                }
            }
            bf16x8 bfr[2];
#pragma unroll
            for (int j = 0; j < 2; ++j)
                bfr[j] = *(const bf16x8*)(sb + ((ks * 2 + j) * 64 + (lane ^ (ks << 1))) * 8);
#pragma unroll
            for (int i = 0; i < 4; ++i)
#pragma unroll
                for (int j = 0; j < 2; ++j)
                    acc[i][j] = __builtin_amdgcn_mfma_f32_16x16x32_bf16(a[i], bfr[j], acc[i][j], 0, 0, 0);
        }
        // no trailing barrier: next iter writes the OTHER LDS buffer
    }

    // ---- epilogue: + bias, store fp32 ----
#pragma unroll
    for (int j = 0; j < 2; ++j) {
        const int n = n0 + j * 16 + ln;
        const float bv = bias[n];
#pragma unroll
        for (int i = 0; i < 4; ++i) {
            const int mbase = w * 64 + i * 16 + quad * 4;
#pragma unroll
            for (int rr = 0; rr < 4; ++rr)
                out[(size_t)(mbase + rr) * NN + n] = acc[i][j][rr] + bv;
        }
    }
}

extern "C" void kernel_launch(void* const* d_in, const int* in_sizes, int n_in,
                              void* d_out, int out_size, void* d_ws, size_t ws_size,
                              hipStream_t stream) {
    const float* x    = (const float*)d_in[0];
    const int* qw     = (const int*)d_in[1];
    const float* scl  = (const float*)d_in[2];
    const float* bias = (const float*)d_in[3];
    float* out        = (float*)d_out;

    dim3 grid(NN / BN);    // 512 blocks: one 32-col slab each, all 512 rows -> 2 blocks/CU
    dim3 block(512);       // 8 waves

    if (ws_size >= (size_t)MM * KK * sizeof(unsigned short)) {
        unsigned short* xp = (unsigned short*)d_ws;
        pack_x<<<dim3(MM * KK / (256 * 8)), dim3(256), 0, stream>>>(x, xp);
        qlin_gemm<true><<<grid, block, 0, stream>>>(x, xp, qw, scl, bias, out);
    } else {
        qlin_gemm<false><<<grid, block, 0, stream>>>(x, nullptr, qw, scl, bias, out);
    }
}